// Round 13
// baseline (101.248 us; speedup 1.0000x reference)
//
#include <hip/hip_runtime.h>
#include <hip/hip_bf16.h>

typedef unsigned int u32;
typedef unsigned short u16;
typedef float f32x2 __attribute__((ext_vector_type(2)));
typedef float f32x4 __attribute__((ext_vector_type(4)));
using bf16x8 = __attribute__((ext_vector_type(8))) short;   // MFMA A/B frag (4 VGPRs)
using f32x4v = __attribute__((ext_vector_type(4))) float;   // MFMA C/D frag

#define DEVINL __device__ __forceinline__

// Problem constants: B=8, C=64, D=128, H=128, W=128
// d-split: each k_A/k_B block handles 64 channels (e = 0 or 1).
constexpr int SCAN_LDS = 32768;        // bufA(16K) + bufB(16K)
constexpr int XS = 132;                // k_final transpose staging stride (u16)
constexpr int LDS_X = 128 * XS * 2;    // 33792

DEVINL float bf2f(u16 u) { union { u32 i; float f; } v; v.i = ((u32)u) << 16; return v.f; }
DEVINL float bf2f_lo(u32 u) { union { u32 i; float f; } v; v.i = u << 16; return v.f; }
DEVINL float bf2f_hi(u32 u) { union { u32 i; float f; } v; v.i = u & 0xffff0000u; return v.f; }
DEVINL u16 f2bf(float f) {
  __hip_bfloat16 h = __float2bfloat16(f);
  u16 r; __builtin_memcpy(&r, &h, 2); return r;
}
DEVINL u32 pack2(float a, float b) { return (u32)f2bf(a) | ((u32)f2bf(b) << 16); }

// ---------------- P0: A=tanh(A_param), Mrow[dir][c][d] bf16, beff, Wi_bf ----------------
__global__ __launch_bounds__(256) void k_pre(
    const float* __restrict__ Wf, const float* __restrict__ Wo,
    const float* __restrict__ bf_, const float* __restrict__ bo,
    const float* __restrict__ A_param, const float* __restrict__ Wi,
    float* __restrict__ A_t, float* __restrict__ beff,
    u16* __restrict__ Mrow, u16* __restrict__ Wi_bf) {
  const int wg = blockIdx.x, t = threadIdx.x;
  if (wg < 128) {
    const int idx = wg * 256 + t;          // 0..32767
    const int cout = idx >> 9;             // 0..63
    const int k = idx & 511;               // dir*128 + d
    float s = 0.f;
    for (int d = 0; d < 128; ++d) s = fmaf(Wo[cout * 128 + d], Wf[d * 512 + k], s);
    const int dir = k >> 7, dm = k & 127;
    Mrow[(dir * 64 + cout) * 128 + dm] = f2bf(s);
  } else if (wg == 128) {
    if (t < 128) A_t[t] = tanhf(A_param[t]);
    if (t < 64) {
      float s = bo[t];
      for (int d = 0; d < 128; ++d) s = fmaf(Wo[t * 128 + d], bf_[d], s);
      beff[t] = s;
    }
  } else {
    // Wi[128 d][64 c] f32 -> bf16, same layout
#pragma unroll
    for (int k = 0; k < 32; ++k) {
      const int i = t + k * 256;
      Wi_bf[i] = f2bf(Wi[i]);
    }
  }
}

extern __shared__ char smem[];

// ---- Chunked scan: local pass (pk math). buf = [128 pos][128B] swz; dp = u32 pair column.
template <bool REV>
DEVINL void scan_local(char* buf, int dp, int chunk, f32x2 A2, f32x2 B2) {
  f32x2 h = { 0.f, 0.f };
  const u32 cb = (u32)(dp * 4);
  const int s = chunk * 32;
  u32 nx[8];
#pragma unroll
  for (int j = 0; j < 8; ++j) {
    const int i = REV ? (127 - (s + j)) : (s + j);
    nx[j] = *(const u32*)(buf + i * 128 + (cb ^ ((u32)((i & 7) << 4))));
  }
  for (int ib = 0; ib < 32; ib += 8) {
    u32 cur[8];
#pragma unroll
    for (int j = 0; j < 8; ++j) cur[j] = nx[j];
    if (ib + 8 < 32) {
#pragma unroll
      for (int j = 0; j < 8; ++j) {
        const int i2 = s + ib + 8 + j;
        const int i = REV ? (127 - i2) : i2;
        nx[j] = *(const u32*)(buf + i * 128 + (cb ^ ((u32)((i & 7) << 4))));
      }
    }
#pragma unroll
    for (int j = 0; j < 8; ++j) {
      const int i2 = s + ib + j;
      const int i = REV ? (127 - i2) : i2;
      const f32x2 xv = { bf2f_lo(cur[j]), bf2f_hi(cur[j]) };
      h = A2 * h + B2 * xv;                       // v_pk_fma_f32 path
      *(u32*)(buf + i * 128 + (cb ^ ((u32)((i & 7) << 4)))) = pack2(h.x, h.y);
    }
  }
}

// ---- Chunked scan: carry correction (pk math). h_i = l_i + A^{j+1} * C.
template <bool REV>
DEVINL void scan_fix(char* buf, int dp, int chunk, f32x2 A2) {
  if (chunk == 0) return;
  f32x2 q = A2;
#pragma unroll
  for (int k = 0; k < 5; ++k) q *= q;            // A^32
  const u32 cb = (u32)(dp * 4);
  f32x2 C = { 0.f, 0.f };
  for (int k = 0; k < chunk; ++k) {
    const int i2 = k * 32 + 31;
    const int i = REV ? (127 - i2) : i2;
    const u32 v = *(const u32*)(buf + i * 128 + (cb ^ ((u32)((i & 7) << 4))));
    const f32x2 xv = { bf2f_lo(v), bf2f_hi(v) };
    C = C * q + xv;
  }
  f32x2 p = A2;
  const int s = chunk * 32;
  u32 nx[8];
#pragma unroll
  for (int j = 0; j < 8; ++j) {
    const int i = REV ? (127 - (s + j)) : (s + j);
    nx[j] = *(const u32*)(buf + i * 128 + (cb ^ ((u32)((i & 7) << 4))));
  }
  for (int ib = 0; ib < 32; ib += 8) {
    u32 cur[8];
#pragma unroll
    for (int j = 0; j < 8; ++j) cur[j] = nx[j];
    if (ib + 8 < 32) {
#pragma unroll
      for (int j = 0; j < 8; ++j) {
        const int i2 = s + ib + 8 + j;
        const int i = REV ? (127 - i2) : i2;
        nx[j] = *(const u32*)(buf + i * 128 + (cb ^ ((u32)((i & 7) << 4))));
      }
    }
#pragma unroll
    for (int j = 0; j < 8; ++j) {
      const int i2 = s + ib + j;
      const int i = REV ? (127 - i2) : i2;
      const f32x2 xv = { bf2f_lo(cur[j]), bf2f_hi(cur[j]) };
      const f32x2 hv = p * C + xv;
      *(u32*)(buf + i * 128 + (cb ^ ((u32)((i & 7) << 4)))) = pack2(hv.x, hv.y);
      p *= A2;
    }
  }
}

// Both scans for a block: dir0 = fwd on bufA, dir1 = rev on bufB; 4 chunks each.
DEVINL void run_scans(char* bufA, char* bufB, int t, int e,
                      const float* __restrict__ A_t, const float* __restrict__ Bp) {
  const int dp = t & 31, chunk = (t >> 5) & 3, dir = t >> 7;
  const int dgp = e * 64 + dp * 2;
  const f32x2 a = *(const f32x2*)(A_t + dgp);
  const f32x2 bb = *(const f32x2*)(Bp + dgp);
  char* sb = dir ? bufB : bufA;
  if (dir == 0) scan_local<false>(sb, dp, chunk, a, bb);
  else          scan_local<true >(sb, dp, chunk, a, bb);
  __syncthreads();
  if (dir == 0) scan_fix<false>(sb, dp, chunk, a);
  else          scan_fix<true >(sb, dp, chunk, a);
}

// acc2 += h @ M[dir] in D[pos][c] orientation (h as A-operand, M as B-operand).
DEVINL void combine64(const char* buf, const u16* __restrict__ Mrow, int dir, int e,
                      int lane, int wv, f32x4v (&acc2)[4][2]) {
  const int l15 = lane & 15, kg = lane >> 4;
#pragma unroll
  for (int ks = 0; ks < 2; ++ks) {
    bf16x8 afr[4], bfr[2];
#pragma unroll
    for (int ct = 0; ct < 4; ++ct)
      afr[ct] = *(const bf16x8*)(Mrow + ((size_t)dir * 64 + ct * 16 + l15) * 128 + e * 64 + ks * 32 + kg * 8);
#pragma unroll
    for (int pt = 0; pt < 2; ++pt) {
      const int row = wv * 32 + pt * 16 + l15;
      bfr[pt] = *(const bf16x8*)(buf + row * 128 + ((u32)(ks * 64 + kg * 16) ^ ((u32)((row & 7) << 4))));
    }
#pragma unroll
    for (int ct = 0; ct < 4; ++ct)
#pragma unroll
      for (int pt = 0; pt < 2; ++pt)
        acc2[ct][pt] = __builtin_amdgcn_mfma_f32_16x16x32_bf16(bfr[pt], afr[ct], acc2[ct][pt], 0, 0, 0);
  }
}

// Direct global write of combine acc: og[c][pos] bf16, thread's f32x4 = 4 consecutive pos.
DEVINL void acc_to_global(const f32x4v (&acc2)[4][2], int lane, int wv, u16* __restrict__ og) {
  const int l15 = lane & 15, kg = lane >> 4;
#pragma unroll
  for (int ct = 0; ct < 4; ++ct)
#pragma unroll
    for (int pt = 0; pt < 2; ++pt) {
      const int c = ct * 16 + l15;
      const int pos = wv * 32 + pt * 16 + kg * 4;
      uint2 pk;
      pk.x = pack2(acc2[ct][pt][0], acc2[ct][pt][1]);
      pk.y = pack2(acc2[ct][pt][2], acc2[ct][pt][3]);
      *(uint2*)(og + c * 128 + pos) = pk;
    }
}

// ---------------- K_A: x-GEMM (64 d half) + horizontal scans + combine ----------------
// bid = ((b*128)+h)*2+e. Writes x2[bid][w][64] and Shp[bid][c][w] (both 16 KB streams).
__global__ __launch_bounds__(256, 5) void k_A(
    const float* __restrict__ F_in, const float* __restrict__ prior,
    const u16* __restrict__ Wi_bf, const float* __restrict__ bi,
    const float* __restrict__ Bp, const float* __restrict__ alpha_p,
    const float* __restrict__ A_t, const u16* __restrict__ Mrow,
    u16* __restrict__ x2, u16* __restrict__ Shp) {
  char* bufA = smem;            // 16 KB [128][128B] swz: x -> h_lr
  char* bufB = smem + 16384;    // 16 KB: x copy -> h_rl

  const int t = threadIdx.x;
  const int lane = t & 63, wv = t >> 6, l15 = lane & 15, kg = lane >> 4;
  const int bid = blockIdx.x;
  const int b = bid >> 8, h = (bid >> 1) & 127, e = bid & 1;

  // ---- P1: F B-frags DIRECT from global (coalesced: 16 lanes x consecutive w) ----
  const float alpha = alpha_p[0];
  bf16x8 bF[2][2];   // [wj][ks]
#pragma unroll
  for (int wj = 0; wj < 2; ++wj) {
    const int w = wv * 32 + wj * 16 + l15;
    const float pv = prior[(b * 128 + h) * 128 + w];
    const float* Fp0 = F_in + (size_t)b * 1048576 + h * 128 + w;
#pragma unroll
    for (int ks = 0; ks < 2; ++ks) {
      const float* Fp = Fp0 + (size_t)(ks * 32 + kg * 8) * 16384;
      float fv[8];
#pragma unroll
      for (int j = 0; j < 8; ++j) fv[j] = fmaf(alpha, pv, Fp[(size_t)j * 16384]);
      union { bf16x8 v; uint4 u; } cv;
      cv.u.x = pack2(fv[0], fv[1]); cv.u.y = pack2(fv[2], fv[3]);
      cv.u.z = pack2(fv[4], fv[5]); cv.u.w = pack2(fv[6], fv[7]);
      bF[wj][ks] = cv.v;
    }
  }

  // ---- P2: GEMM D[d][w]; write x to global + both LDS bufs straight from regs ----
  {
    f32x4v acc[4][2];   // [dt][wj]
#pragma unroll
    for (int dt = 0; dt < 4; ++dt) {
      const f32x4 bv = *(const f32x4*)(bi + e * 64 + dt * 16 + kg * 4);
      const f32x4v bvv = { bv.x, bv.y, bv.z, bv.w };
#pragma unroll
      for (int wj = 0; wj < 2; ++wj) acc[dt][wj] = bvv;
    }
#pragma unroll
    for (int ks = 0; ks < 2; ++ks)
#pragma unroll
      for (int dt = 0; dt < 4; ++dt) {
        const bf16x8 aWi = *(const bf16x8*)(Wi_bf + (e * 64 + dt * 16 + l15) * 64 + ks * 32 + kg * 8);
        acc[dt][0] = __builtin_amdgcn_mfma_f32_16x16x32_bf16(aWi, bF[0][ks], acc[dt][0], 0, 0, 0);
        acc[dt][1] = __builtin_amdgcn_mfma_f32_16x16x32_bf16(aWi, bF[1][ks], acc[dt][1], 0, 0, 0);
      }
    u16* xg = x2 + (size_t)bid * 8192;
#pragma unroll
    for (int dt = 0; dt < 4; ++dt)
#pragma unroll
      for (int wj = 0; wj < 2; ++wj) {
        const int w = wv * 32 + wj * 16 + l15;
        const int dl = dt * 16 + kg * 4;          // d_local base
        uint2 pk;
        pk.x = pack2(acc[dt][wj][0], acc[dt][wj][1]);
        pk.y = pack2(acc[dt][wj][2], acc[dt][wj][3]);
        *(uint2*)(xg + w * 64 + dl) = pk;          // global x2 (8B, merged lines)
        const u32 col = (u32)(dl * 2) ^ ((u32)((w & 7) << 4));
        *(uint2*)(bufA + w * 128 + col) = pk;
        *(uint2*)(bufB + w * 128 + col) = pk;
      }
  }
  __syncthreads();

  // ---- P3: chunk-parallel scans (all 256 threads; internal barrier) ----
  run_scans(bufA, bufB, t, e, A_t, Bp);
  __syncthreads();

  // ---- P4: combine dir0 (bufA) + dir1 (bufB); write Shp direct from regs ----
  f32x4v acc2[4][2];
#pragma unroll
  for (int i = 0; i < 4; ++i)
#pragma unroll
    for (int j = 0; j < 2; ++j) acc2[i][j] = (f32x4v)0.f;
  combine64(bufA, Mrow, 0, e, lane, wv, acc2);
  combine64(bufB, Mrow, 1, e, lane, wv, acc2);
  acc_to_global(acc2, lane, wv, Shp + (size_t)bid * 8192);
}

// ---------------- K_B: vertical scans + combine -> Svp[bid][c][h] ----------------
// bid = ((b*128)+w)*2+e.
__global__ __launch_bounds__(256, 5) void k_B(
    const u16* __restrict__ x2, const float* __restrict__ Bp,
    const float* __restrict__ A_t, const u16* __restrict__ Mrow,
    u16* __restrict__ Svp) {
  char* bufA = smem;
  char* bufB = smem + 16384;
  const int t = threadIdx.x;
  const int lane = t & 63, wv = t >> 6;
  const int bid = blockIdx.x;
  const int b = bid >> 8, w = (bid >> 1) & 127, e = bid & 1;

  // ---- P1: stage x rows (h-major) into both buffers; 16B L3-hot segments ----
#pragma unroll
  for (int j = 0; j < 4; ++j) {
    const int idx = t + j * 256;
    const int hh = idx >> 3, q = idx & 7;
    const uint4 v = *(const uint4*)(x2 + ((size_t)((b * 128 + hh) * 2 + e)) * 8192 + w * 64 + q * 8);
    const u32 col = (u32)(q * 16) ^ ((u32)((hh & 7) << 4));
    *(uint4*)(bufA + hh * 128 + col) = v;
    *(uint4*)(bufB + hh * 128 + col) = v;
  }
  __syncthreads();

  // ---- P2: chunk-parallel scans ----
  run_scans(bufA, bufB, t, e, A_t, Bp);
  __syncthreads();

  // ---- P3: combine dir2 (bufA) + dir3 (bufB); write Svp direct from regs ----
  f32x4v acc2[4][2];
#pragma unroll
  for (int i = 0; i < 4; ++i)
#pragma unroll
    for (int j = 0; j < 2; ++j) acc2[i][j] = (f32x4v)0.f;
  combine64(bufA, Mrow, 2, e, lane, wv, acc2);
  combine64(bufB, Mrow, 3, e, lane, wv, acc2);
  acc_to_global(acc2, lane, wv, Svp + (size_t)bid * 8192);
}

// ---------------- F: out = F_mod + gamma*(Sh0+Sh1 + (Sv0+Sv1)^T + beff) ----------------
__global__ __launch_bounds__(256) void k_final(
    const float* __restrict__ F_in, const float* __restrict__ prior,
    const float* __restrict__ alpha_p, const float* __restrict__ gamma_p,
    const float* __restrict__ beff, const u16* __restrict__ Svp,
    const u16* __restrict__ Shp, float* __restrict__ out) {
  u16* Xu = (u16*)smem;
  const int t = threadIdx.x;
  const int bid = blockIdx.x, b = bid >> 6, c = bid & 63;
  const size_t base = (size_t)bid * 16384;   // (b,c) plane of out/F

  // stage Sv = Svp(e0)+Svp(e1), transposed via LDS: Xu[w][h], stride 132
  for (int i = t; i < 2048; i += 256) {
    const int w = i >> 4, q = i & 15;
    const u16* s0 = Svp + ((size_t)((b * 128 + w) * 2)) * 8192 + c * 128 + q * 8;
    const uint4 a4 = *(const uint4*)(s0);
    const uint4 b4 = *(const uint4*)(s0 + 8192);
    const u16* ap = (const u16*)&a4;
    const u16* bp = (const u16*)&b4;
    u32* dst = (u32*)(Xu + w * 132 + q * 8);
#pragma unroll
    for (int k = 0; k < 4; ++k) {
      const float lo = bf2f(ap[k * 2]) + bf2f(bp[k * 2]);
      const float hi = bf2f(ap[k * 2 + 1]) + bf2f(bp[k * 2 + 1]);
      dst[k] = pack2(lo, hi);
    }
  }
  __syncthreads();
  const float alpha = alpha_p[0], gamma = gamma_p[0];
  const float be = beff[c];
  for (int i = t; i < 2048; i += 256) {
    const int hh = i >> 4, w8 = (i & 15) * 8;
    const size_t off = base + hh * 128 + w8;
    const u16* sh0 = Shp + ((size_t)((b * 128 + hh) * 2)) * 8192 + c * 128 + w8;
    const uint4 g0 = *(const uint4*)(sh0);
    const uint4 g1 = *(const uint4*)(sh0 + 8192);
    const u16* p0 = (const u16*)&g0;
    const u16* p1 = (const u16*)&g1;
    const float* Fp = F_in + off;
    float* Op = out + off;
    const float* Pp = prior + (b * 128 + hh) * 128 + w8;
#pragma unroll
    for (int q = 0; q < 8; ++q) {
      const float sv = bf2f(Xu[(w8 + q) * 132 + hh]);
      Op[q] = Fp[q] + alpha * Pp[q] + gamma * (bf2f(p0[q]) + bf2f(p1[q]) + sv + be);
    }
  }
}

extern "C" void kernel_launch(void* const* d_in, const int* in_sizes, int n_in,
                              void* d_out, int out_size, void* d_ws, size_t ws_size,
                              hipStream_t stream) {
  const float* F_in   = (const float*)d_in[0];
  const float* prior  = (const float*)d_in[1];
  const float* Wi     = (const float*)d_in[2];
  const float* bi     = (const float*)d_in[3];
  const float* A_par  = (const float*)d_in[4];
  const float* B_par  = (const float*)d_in[5];
  const float* alpha  = (const float*)d_in[6];
  const float* gamma  = (const float*)d_in[7];
  const float* Wf     = (const float*)d_in[8];
  const float* bf_    = (const float*)d_in[9];
  const float* Wo     = (const float*)d_in[10];
  const float* bo     = (const float*)d_in[11];
  float* out = (float*)d_out;

  char* ws = (char*)d_ws;
  float* A_t   = (float*)ws;                        // 512 B
  float* beff  = (float*)(ws + 512);                // 256 B
  u16*   Mrow  = (u16*)(ws + 1024);                 // 64 KB: [4][64][128] bf16
  u16*   Wi_bf = (u16*)(ws + 66560);                // 16 KB: [128][64] bf16
  u16*   x2    = (u16*)(ws + 82944);                // 33.5 MB: [2048][128 w][64 d]
  u16*   Shp   = (u16*)(ws + 82944 + 33554432);     // 33.5 MB: [2048][64 c][128 w]
  u16*   Svp   = (u16*)(ws + 82944 + 67108864);     // 33.5 MB: [2048][64 c][128 h]

  hipFuncSetAttribute((const void*)k_A, hipFuncAttributeMaxDynamicSharedMemorySize, SCAN_LDS);
  hipFuncSetAttribute((const void*)k_B, hipFuncAttributeMaxDynamicSharedMemorySize, SCAN_LDS);

  k_pre  <<<130, 256, 0, stream>>>(Wf, Wo, bf_, bo, A_par, Wi, A_t, beff, Mrow, Wi_bf);
  k_A    <<<2048, 256, SCAN_LDS, stream>>>(F_in, prior, Wi_bf, bi, B_par, alpha, A_t, Mrow, x2, Shp);
  k_B    <<<2048, 256, SCAN_LDS, stream>>>(x2, B_par, A_t, Mrow, Svp);
  k_final<<<512, 256, LDS_X, stream>>>(F_in, prior, alpha, gamma, beff, Svp, Shp, out);
}